// Round 8
// baseline (198.554 us; speedup 1.0000x reference)
//
#include <hip/hip_runtime.h>
#include <math.h>

#define BB 32
#define LL 512
#define DD 32
#define KK 6
#define OO 192
#define DM 512

typedef __fp16 h2 __attribute__((ext_vector_type(2)));
union F2H { float f; h2 h; };
__device__ __forceinline__ float asF(h2 h) { F2H u; u.h = h; return u.f; }
__device__ __forceinline__ h2 asH(float f) { F2H u; u.f = f; return u.h; }

#define MOVDPP(x, ctrl) \
  __int_as_float(__builtin_amdgcn_mov_dpp(__float_as_int(x), ctrl, 0xf, 0xf, true))

// LDS layout (float slots) for fused kernel
#define CSTR  520
#define XCOL  0                 // 7 cols x 520 f32; cols 0-5 overlaid by f16 rows later
#define XV    3120              // = XCOL + 6*CSTR : x column stays f32
#define YDMB  3648              // 192 x 4 (packed y f16); overlaid by DEN/NUM 2x768
#define BNP   5184              // 8 floats bn partials (overlays dead MEDO/STDO)
#define MEDO  5184
#define STDO  5191
#define SAO   5198
#define SCO   5204
#define LDSF  5216              // 20.9 KB

// ---------------------------------------------------------------------------
// Prep: x_date (b,l,dk) -> xt (b,dk,l) coalesced tiled transpose. 512 blocks.
// (x and y_date are read directly by fused: their strided reads are tiny and
//  L2-absorbed — R6 FETCH evidence.)
// ---------------------------------------------------------------------------
__global__ __launch_bounds__(256) void prep_kernel(
    const float* __restrict__ x_date, float* __restrict__ xt) {
  __shared__ float tl[32 * 196];
  int bid = blockIdx.x, tid = threadIdx.x;
  int b = bid >> 4, l0 = (bid & 15) * 32;
  const float* src = x_date + (size_t)(b * LL + l0) * 192;
  #pragma unroll
  for (int it = 0; it < 6; ++it) {            // 32 rows x 48 float4 reads
    int f = tid + it * 256;
    int row = f / 48, c4 = f % 48;
    float4 v = ((const float4*)(src + (size_t)row * 192))[c4];
    float* p = &tl[row * 196 + c4 * 4];
    p[0] = v.x; p[1] = v.y; p[2] = v.z; p[3] = v.w;
  }
  __syncthreads();
  #pragma unroll
  for (int it = 0; it < 6; ++it) {            // 192 dk x 8 float4 writes
    int f = tid + it * 256;
    int dk = f / 8, c4 = f % 8;
    float4 v;
    v.x = tl[(c4 * 4 + 0) * 196 + dk];
    v.y = tl[(c4 * 4 + 1) * 196 + dk];
    v.z = tl[(c4 * 4 + 2) * 196 + dk];
    v.w = tl[(c4 * 4 + 3) * 196 + dk];
    ((float4*)(xt + (size_t)(b * 192 + dk) * LL + l0))[c4] = v;
  }
}

// ---------------------------------------------------------------------------
// In-register bitonic sort of 512 floats across one wave (8 elems/lane).
// Lane-xor 1/2/8 via DPP (VALU pipe); 4/16/32 via shfl (LDS pipe).
// ---------------------------------------------------------------------------
__device__ __forceinline__ void sort512(float v[8], int lane) {
  #pragma unroll
  for (int k = 2; k <= 512; k <<= 1) {
    #pragma unroll
    for (int j = k >> 1; j > 0; j >>= 1) {
      if (j >= 8) {
        int jj = j >> 3;
        bool lower = (lane & jj) == 0;
        bool asc = ((lane << 3) & k) == 0;
        bool keepmin = (asc == lower);
        #pragma unroll
        for (int r = 0; r < 8; ++r) {
          float o;
          if (jj == 1)      o = MOVDPP(v[r], 0xB1);   // quad_perm [1,0,3,2]
          else if (jj == 2) o = MOVDPP(v[r], 0x4E);   // quad_perm [2,3,0,1]
          else if (jj == 8) o = MOVDPP(v[r], 0x128);  // row_ror:8 == xor8
          else              o = __shfl_xor(v[r], jj);
          v[r] = keepmin ? fminf(v[r], o) : fmaxf(v[r], o);
        }
      } else {
        #pragma unroll
        for (int r = 0; r < 8; ++r) {
          if ((r & j) == 0) {
            int r2 = r | j;
            bool asc = (((lane << 3) | r) & k) == 0;
            float a = v[r], b = v[r2];
            float lo = fminf(a, b), hi = fmaxf(a, b);
            v[r]  = asc ? lo : hi;
            v[r2] = asc ? hi : lo;
          }
        }
      }
    }
  }
}

// ---------------------------------------------------------------------------
// Fused: per-(b,d) order stats + affine map + attention + err + ymean + bn
// partial sums (atomicAdd). R6 structure (58us) + DPP sort + direct x/y reads.
// ---------------------------------------------------------------------------
__global__ __launch_bounds__(256) void fused_kernel(
    const float* __restrict__ x, const float* __restrict__ xt,
    const float* __restrict__ y_date,
    float* __restrict__ V, float* __restrict__ ymean, float* __restrict__ errt,
    float* __restrict__ accum) {
  __shared__ float lds[LDSF];
  int bid = blockIdx.x, b = bid >> 5, d = bid & 31;
  int tid = threadIdx.x, lane = tid & 63, wv = tid >> 6;

  // ---- stage 6 contiguous xt rows into LDS cols; x strided into col 6 ----
  const float* xtb = xt + (size_t)(b * 192 + d * 6) * LL;
  #pragma unroll
  for (int it = 0; it < 3; ++it) {
    int f = tid + it * 256;                    // 0..767 = 6 cols x 128 float4
    int c = f >> 7, c4 = f & 127;
    float4 v = ((const float4*)(xtb + (size_t)c * LL))[c4];
    *(float4*)&lds[XCOL + c * CSTR + c4 * 4] = v;
  }
  const float* xp = x + (size_t)b * LL * DD + d;
  lds[XV + tid]       = xp[(size_t)tid * DD];
  lds[XV + tid + 256] = xp[(size_t)(tid + 256) * DD];
  __syncthreads();

  // ---- sort 7 sequences (2 passes of 4 waves) ----
  #pragma unroll
  for (int pass = 0; pass < 2; ++pass) {
    int s = pass * 4 + wv;
    if (s < 7) {
      float v[8];
      const float4* colp = (const float4*)&lds[XCOL + s * CSTR + lane * 8];
      float4 c0 = colp[0], c1 = colp[1];
      v[0]=c0.x; v[1]=c0.y; v[2]=c0.z; v[3]=c0.w;
      v[4]=c1.x; v[5]=c1.y; v[6]=c1.z; v[7]=c1.w;
      sort512(v, lane);
      float e127 = __shfl(v[7], 15);
      float e128 = __shfl(v[0], 16);
      float e255 = __shfl(v[7], 31);
      float e383 = __shfl(v[7], 47);
      float e384 = __shfl(v[0], 48);
      if (lane == 0) {
        float q25 = e127 + 0.75f * (e128 - e127);   // 0.25*(n-1)=127.75
        float q75 = e383 + 0.25f * (e384 - e383);   // 0.75*(n-1)=383.25
        lds[MEDO + s] = e255;                       // torch lower-median
        lds[STDO + s] = q75 - q25 + 1e-6f;
      }
    }
  }
  __syncthreads();

  if (tid < 6) {
    float a = lds[STDO + 6] / lds[STDO + tid];
    lds[SAO + tid] = a;
    lds[SCO + tid] = lds[MEDO + 6] - lds[MEDO + tid] * a;
  }
  __syncthreads();

  float ask[6], csk[6];
  #pragma unroll
  for (int k = 0; k < 6; ++k) { ask[k] = lds[SAO + k]; csk[k] = lds[SCO + k]; }

  const float PSC = 0.58912435f;   // (1/sqrt(6)) * log2(e)

  // ---- transform rows tid, tid+256 into regs (f16-packed, x-side prescaled) ----
  float4 packed[2];
  #pragma unroll
  for (int it = 0; it < 2; ++it) {
    int l = tid + it * 256;
    float m0 = ask[0]*lds[XCOL+0*CSTR+l] + csk[0];
    float m1 = ask[1]*lds[XCOL+1*CSTR+l] + csk[1];
    float m2 = ask[2]*lds[XCOL+2*CSTR+l] + csk[2];
    float m3 = ask[3]*lds[XCOL+3*CSTR+l] + csk[3];
    float m4 = ask[4]*lds[XCOL+4*CSTR+l] + csk[4];
    float m5 = ask[5]*lds[XCOL+5*CSTR+l] + csk[5];
    float xvv = lds[XV + l];
    errt[(size_t)bid * LL + l] = xvv - (m0+m1+m2+m3+m4+m5) * (1.0f/6.0f);
    packed[it].x = asF(__builtin_amdgcn_cvt_pkrtz(m0*PSC, m1*PSC));
    packed[it].y = asF(__builtin_amdgcn_cvt_pkrtz(m2*PSC, m3*PSC));
    packed[it].z = asF(__builtin_amdgcn_cvt_pkrtz(m4*PSC, m5*PSC));
    packed[it].w = asF(__builtin_amdgcn_cvt_pkrtz(xvv, 0.0f));
  }

  // ---- y staging (threads 0..191): direct strided reads (L2-absorbed) ----
  float4 ypk; float ymv; bool doY = (tid < OO);
  if (doY) {
    const float2* yp = (const float2*)(y_date + (((size_t)b * OO + tid) * DD + d) * KK);
    float2 y0 = yp[0], y1 = yp[1], y2 = yp[2];
    float q0 = ask[0]*y0.x + csk[0];
    float q1 = ask[1]*y0.y + csk[1];
    float q2 = ask[2]*y1.x + csk[2];
    float q3 = ask[3]*y1.y + csk[3];
    float q4 = ask[4]*y2.x + csk[4];
    float q5 = ask[5]*y2.y + csk[5];
    ymv = (q0+q1+q2+q3+q4+q5) * (1.0f/6.0f);
    ypk.x = asF(__builtin_amdgcn_cvt_pkrtz(q0, q1));
    ypk.y = asF(__builtin_amdgcn_cvt_pkrtz(q2, q3));
    ypk.z = asF(__builtin_amdgcn_cvt_pkrtz(q4, q5));
  }
  __syncthreads();   // all XCOL col0-5 reads done; safe to overlay

  // ---- write f16 rows (overlay XCOL cols 0-5) + YDM; load yk frags ----
  *(float4*)&lds[tid * 4]         = packed[0];
  *(float4*)&lds[(tid + 256) * 4] = packed[1];
  if (doY) {
    ymean[(size_t)bid * OO + tid] = ymv;
    lds[YDMB + tid*4 + 0] = ypk.x;
    lds[YDMB + tid*4 + 1] = ypk.y;
    lds[YDMB + tid*4 + 2] = ypk.z;
  }
  __syncthreads();

  h2 yk[3][3];
  #pragma unroll
  for (int j = 0; j < 3; ++j) {
    int o = lane + 64 * j;
    yk[j][0] = asH(lds[YDMB + o*4 + 0]);
    yk[j][1] = asH(lds[YDMB + o*4 + 1]);
    yk[j][2] = asH(lds[YDMB + o*4 + 2]);
  }
  __syncthreads();   // yk loaded; DEN/NUM may overlay YDM after this

  // ---- attention: wave wv handles l in [wv*128, +128), 3 o's/lane ----
  float den[3] = {0.f,0.f,0.f}, num[3] = {0.f,0.f,0.f};
  int l0 = wv * 128;
  #pragma unroll 2
  for (int l = l0; l < l0 + 128; ++l) {
    float4 rw = *(const float4*)&lds[l * 4];
    h2 x01 = asH(rw.x), x23 = asH(rw.y), x45 = asH(rw.z);
    float xf = (float)(asH(rw.w).x);
    #pragma unroll
    for (int j = 0; j < 3; ++j) {
      float sc = __builtin_amdgcn_fdot2(x01, yk[j][0], 0.0f, false);
      sc = __builtin_amdgcn_fdot2(x23, yk[j][1], sc, false);
      sc = __builtin_amdgcn_fdot2(x45, yk[j][2], sc, false);
      float e = exp2f(sc);     // scale folded into x-side pack
      den[j] += e;
      num[j] += e * xf;
    }
  }
  #pragma unroll
  for (int j = 0; j < 3; ++j) {
    lds[YDMB + wv*192 + lane + 64*j]       = den[j];
    lds[YDMB + 768 + wv*192 + lane + 64*j] = num[j];
  }
  __syncthreads();

  float v = 0.0f;
  if (tid < OO) {
    float dsum = lds[YDMB + tid] + lds[YDMB + 192 + tid]
               + lds[YDMB + 384 + tid] + lds[YDMB + 576 + tid];
    float nsum = lds[YDMB + 768 + tid] + lds[YDMB + 960 + tid]
               + lds[YDMB + 1152 + tid] + lds[YDMB + 1344 + tid];
    v = nsum / dsum;
    V[(size_t)bid * OO + tid] = v;
  }

  // ---- bn partial sums over this block's 192 V values -> atomicAdd per d ----
  __syncthreads();                 // YDMB reads done; BNP overlays safe
  float s1 = v, s2 = v * v;
  #pragma unroll
  for (int off = 32; off > 0; off >>= 1) {
    s1 += __shfl_down(s1, off);
    s2 += __shfl_down(s2, off);
  }
  if (lane == 0) { lds[BNP + wv] = s1; lds[BNP + 4 + wv] = s2; }
  __syncthreads();
  if (tid == 0) {
    float S  = lds[BNP+0] + lds[BNP+1] + lds[BNP+2] + lds[BNP+3];
    float S2 = lds[BNP+4] + lds[BNP+5] + lds[BNP+6] + lds[BNP+7];
    atomicAdd(&accum[d], S);
    atomicAdd(&accum[DD + d], S2);
  }
}

// ---------------------------------------------------------------------------
// Gating MLP: 256 blocks x 512 threads (8 waves), 4 rows/block, m = tid.
// err rows staged in LDS, read as broadcast ds_read_b128 (4 l's per read);
// w1 dwords coalesced (L2-resident). No scalar-load serialization.
// ---------------------------------------------------------------------------
__global__ __launch_bounds__(512) void mlp_kernel(
    const float* __restrict__ errt, const float* __restrict__ w1,
    const float* __restrict__ b1, const float* __restrict__ w2,
    const float* __restrict__ b2, float* __restrict__ w0out) {
  int r0 = blockIdx.x * 4;
  int m = threadIdx.x;
  __shared__ float esh[4 * LL];     // 8 KB

  ((float4*)esh)[m] = ((const float4*)(errt + (size_t)r0 * LL))[m];  // 512 f4

  float bb1 = b1[m];
  float acc0 = bb1, acc1 = bb1, acc2 = bb1, acc3 = bb1;
  __syncthreads();

  const float* wp = w1 + m;
  #pragma unroll 4
  for (int g = 0; g < 128; ++g) {
    float4 e0 = *(const float4*)&esh[0*LL + g*4];
    float4 e1 = *(const float4*)&esh[1*LL + g*4];
    float4 e2 = *(const float4*)&esh[2*LL + g*4];
    float4 e3 = *(const float4*)&esh[3*LL + g*4];
    #pragma unroll
    for (int j = 0; j < 4; ++j) {
      float wvv = wp[(size_t)(g*4 + j) * DM];
      float ej0 = (j==0)?e0.x:(j==1)?e0.y:(j==2)?e0.z:e0.w;
      float ej1 = (j==0)?e1.x:(j==1)?e1.y:(j==2)?e1.z:e1.w;
      float ej2 = (j==0)?e2.x:(j==1)?e2.y:(j==2)?e2.z:e2.w;
      float ej3 = (j==0)?e3.x:(j==1)?e3.y:(j==2)?e3.z:e3.w;
      acc0 += ej0 * wvv;
      acc1 += ej1 * wvv;
      acc2 += ej2 * wvv;
      acc3 += ej3 * wvv;
    }
  }

  float2 w2v = ((const float2*)w2)[m];
  float w2d = w2v.x - w2v.y;
  float p[4];
  {
    float g0 = 0.5f * acc0 * (1.0f + erff(acc0 * 0.70710678f));
    float g1 = 0.5f * acc1 * (1.0f + erff(acc1 * 0.70710678f));
    float g2 = 0.5f * acc2 * (1.0f + erff(acc2 * 0.70710678f));
    float g3 = 0.5f * acc3 * (1.0f + erff(acc3 * 0.70710678f));
    p[0] = g0 * w2d; p[1] = g1 * w2d; p[2] = g2 * w2d; p[3] = g3 * w2d;
  }

  #pragma unroll
  for (int r = 0; r < 4; ++r)
    for (int off = 32; off > 0; off >>= 1)
      p[r] += __shfl_down(p[r], off);

  __shared__ float part[8][4];
  int wave = m >> 6, lane = m & 63;
  if (lane == 0) {
    #pragma unroll
    for (int r = 0; r < 4; ++r) part[wave][r] = p[r];
  }
  __syncthreads();
  if (m < 4) {
    float ld = b2[0] - b2[1];
    #pragma unroll
    for (int wvi = 0; wvi < 8; ++wvi) ld += part[wvi][m];
    w0out[r0 + m] = 1.0f / (1.0f + expf(-ld));
  }
}

// ---------------------------------------------------------------------------
// Final fusion via LDS transpose; computes mu/rstd from global accumulators.
// ---------------------------------------------------------------------------
__global__ __launch_bounds__(256) void final_kernel(
    const float* __restrict__ V, const float* __restrict__ ymean,
    const float* __restrict__ w0, const float* __restrict__ accum,
    const float* __restrict__ gamma, const float* __restrict__ beta,
    float* __restrict__ out) {
  __shared__ float vsh[32 * 100], ysh[32 * 100];
  __shared__ float gate[32], scal[32], offs[32];
  int bid = blockIdx.x, b = bid >> 1, o0 = (bid & 1) * 96;
  int tid = threadIdx.x;

  #pragma unroll
  for (int it = 0; it < 3; ++it) {
    int f = tid + it * 256;
    int d = f / 24, c4 = f % 24;
    size_t goff = (size_t)(b * DD + d) * OO + o0;
    float4 v = ((const float4*)(V + goff))[c4];
    float4 y = ((const float4*)(ymean + goff))[c4];
    float* pv = &vsh[d * 100 + c4 * 4];
    float* py = &ysh[d * 100 + c4 * 4];
    pv[0]=v.x; pv[1]=v.y; pv[2]=v.z; pv[3]=v.w;
    py[0]=y.x; py[1]=y.y; py[2]=y.z; py[3]=y.w;
  }
  if (tid < 32) {
    const float inv = 1.0f / (BB * OO);
    float mu = accum[tid] * inv;
    float var = accum[DD + tid] * inv - mu * mu;
    float g = gamma[tid] * rsqrtf(var + 1e-5f);
    gate[tid] = w0[b * DD + tid];
    scal[tid] = g;
    offs[tid] = beta[tid] - mu * g;
  }
  __syncthreads();

  #pragma unroll
  for (int it = 0; it < 3; ++it) {
    int f = tid + it * 256;
    int op = f / 8, c4 = f % 8;
    float4 r;
    #pragma unroll
    for (int j = 0; j < 4; ++j) {
      int d = c4 * 4 + j;
      float v  = vsh[d * 100 + op];
      float ym = ysh[d * 100 + op];
      float g  = gate[d];
      float y  = v * scal[d] + offs[d];
      ((float*)&r)[j] = ym * g + y * (1.0f - g);
    }
    ((float4*)(out + (size_t)(b * OO + o0 + op) * DD))[c4] = r;
  }
}

// ---------------------------------------------------------------------------
extern "C" void kernel_launch(void* const* d_in, const int* in_sizes, int n_in,
                              void* d_out, int out_size, void* d_ws, size_t ws_size,
                              hipStream_t stream) {
  const float* x      = (const float*)d_in[0];
  const float* x_date = (const float*)d_in[1];
  const float* y_date = (const float*)d_in[2];
  const float* w1     = (const float*)d_in[3];
  const float* b1     = (const float*)d_in[4];
  const float* w2     = (const float*)d_in[5];
  const float* b2     = (const float*)d_in[6];
  const float* gamma  = (const float*)d_in[7];
  const float* beta   = (const float*)d_in[8];
  float* out = (float*)d_out;

  float* ws    = (float*)d_ws;
  float* V     = ws;                 // 196608  (B,D,O)
  float* ymean = ws + 196608;        // 196608  (B,D,O)
  float* errt  = ws + 393216;        // 524288  (B,D,L)
  float* w0    = ws + 917504;        // 1024    (B,D)
  float* accum = ws + 918528;        // 64      (sum, sumsq per d)
  float* xt    = ws + 918592;        // 3145728 (B,192,L)

  hipMemsetAsync(accum, 0, 64 * sizeof(float), stream);
  prep_kernel<<<512, 256, 0, stream>>>(x_date, xt);
  fused_kernel<<<BB * DD, 256, 0, stream>>>(x, xt, y_date, V, ymean, errt, accum);
  mlp_kernel<<<BB * DD / 4, 512, 0, stream>>>(errt, w1, b1, w2, b2, w0);
  final_kernel<<<2 * BB, 256, 0, stream>>>(V, ymean, w0, accum, gamma, beta, out);
}

// Round 9
// 167.356 us; speedup vs baseline: 1.1864x; 1.1864x over previous
//
#include <hip/hip_runtime.h>
#include <math.h>

#define BB 32
#define LL 512
#define DD 32
#define KK 6
#define OO 192
#define DM 512

typedef __fp16 h2 __attribute__((ext_vector_type(2)));
union F2H { float f; h2 h; };
__device__ __forceinline__ float asF(h2 h) { F2H u; u.h = h; return u.f; }
__device__ __forceinline__ h2 asH(float f) { F2H u; u.f = f; return u.h; }

typedef short bf16x8 __attribute__((ext_vector_type(8)));
typedef float f4 __attribute__((ext_vector_type(4)));
union U16x8 { uint4 u; bf16x8 h; };

__device__ __forceinline__ unsigned short f2bf(float x) {   // RNE f32->bf16
  unsigned int u = __float_as_uint(x);
  u = (u + 0x7FFF + ((u >> 16) & 1)) >> 16;
  return (unsigned short)u;
}

#define MOVDPP(x, ctrl) \
  __int_as_float(__builtin_amdgcn_mov_dpp(__float_as_int(x), ctrl, 0xf, 0xf, true))

// LDS layout (float slots) for fused kernel
#define CSTR  520
#define XCOL  0                 // 7 cols x 520 f32; cols 0-5 overlaid by f16 rows later
#define XV    3120              // = XCOL + 6*CSTR : x column stays f32
#define YDMB  3648              // 192 x 4 (packed y f16); overlaid by DEN/NUM 2x768
#define BNP   5184              // 8 floats bn partials (overlays dead MEDO/STDO)
#define MEDO  5184
#define STDO  5191
#define SAO   5198
#define SCO   5204
#define LDSF  5216              // 20.9 KB

// ---------------------------------------------------------------------------
// Prep:
//  bids 0..511  : x_date (b,l,dk) -> xt (b,dk,l) tiled transpose
//  bids 512..575: w1 (l,m) f32 -> w1t (m,l) bf16 tiled transpose (64x64 tiles)
// ---------------------------------------------------------------------------
__global__ __launch_bounds__(256) void prep_kernel(
    const float* __restrict__ x_date, float* __restrict__ xt,
    const float* __restrict__ w1, unsigned short* __restrict__ w1t) {
  __shared__ float tl[32 * 196];
  int bid = blockIdx.x, tid = threadIdx.x;

  if (bid < 512) {
    int b = bid >> 4, l0 = (bid & 15) * 32;
    const float* src = x_date + (size_t)(b * LL + l0) * 192;
    #pragma unroll
    for (int it = 0; it < 6; ++it) {            // 32 rows x 48 float4 reads
      int f = tid + it * 256;
      int row = f / 48, c4 = f % 48;
      float4 v = ((const float4*)(src + (size_t)row * 192))[c4];
      float* p = &tl[row * 196 + c4 * 4];
      p[0] = v.x; p[1] = v.y; p[2] = v.z; p[3] = v.w;
    }
    __syncthreads();
    #pragma unroll
    for (int it = 0; it < 6; ++it) {            // 192 dk x 8 float4 writes
      int f = tid + it * 256;
      int dk = f / 8, c4 = f % 8;
      float4 v;
      v.x = tl[(c4 * 4 + 0) * 196 + dk];
      v.y = tl[(c4 * 4 + 1) * 196 + dk];
      v.z = tl[(c4 * 4 + 2) * 196 + dk];
      v.w = tl[(c4 * 4 + 3) * 196 + dk];
      ((float4*)(xt + (size_t)(b * 192 + dk) * LL + l0))[c4] = v;
    }
  } else {
    // ---- w1 -> w1t bf16, 64x64 tile ----
    int id = bid - 512;                         // 0..63
    int l0 = (id & 7) * 64, m0 = (id >> 3) * 64;
    #pragma unroll
    for (int it = 0; it < 4; ++it) {            // 64 l-rows x 16 float4
      int f = tid + it * 256;
      int row = f >> 4, c4 = f & 15;
      float4 v = ((const float4*)(w1 + (size_t)(l0 + row) * DM + m0))[c4];
      float* p = &tl[row * 68 + c4 * 4];        // tl[l][m], stride 68
      p[0] = v.x; p[1] = v.y; p[2] = v.z; p[3] = v.w;
    }
    __syncthreads();
    unsigned int* w1t32 = (unsigned int*)w1t;
    #pragma unroll
    for (int it = 0; it < 8; ++it) {            // 64 m-rows x 32 uints
      int f = tid + it * 256;
      int mr = f >> 5, c = f & 31;
      float a = tl[(c * 2 + 0) * 68 + mr];
      float b = tl[(c * 2 + 1) * 68 + mr];
      unsigned int u = (unsigned int)f2bf(a) | ((unsigned int)f2bf(b) << 16);
      w1t32[(size_t)(m0 + mr) * (DM / 2) + (l0 >> 1) + c] = u;
    }
  }
}

// ---------------------------------------------------------------------------
// In-register bitonic sort of 512 floats across one wave (8 elems/lane).
// Lane-xor 1/2/8 via DPP (VALU pipe); 4/16/32 via shfl (LDS pipe).
// ---------------------------------------------------------------------------
__device__ __forceinline__ void sort512(float v[8], int lane) {
  #pragma unroll
  for (int k = 2; k <= 512; k <<= 1) {
    #pragma unroll
    for (int j = k >> 1; j > 0; j >>= 1) {
      if (j >= 8) {
        int jj = j >> 3;
        bool lower = (lane & jj) == 0;
        bool asc = ((lane << 3) & k) == 0;
        bool keepmin = (asc == lower);
        #pragma unroll
        for (int r = 0; r < 8; ++r) {
          float o;
          if (jj == 1)      o = MOVDPP(v[r], 0xB1);   // quad_perm [1,0,3,2]
          else if (jj == 2) o = MOVDPP(v[r], 0x4E);   // quad_perm [2,3,0,1]
          else if (jj == 8) o = MOVDPP(v[r], 0x128);  // row_ror:8 == xor8
          else              o = __shfl_xor(v[r], jj);
          v[r] = keepmin ? fminf(v[r], o) : fmaxf(v[r], o);
        }
      } else {
        #pragma unroll
        for (int r = 0; r < 8; ++r) {
          if ((r & j) == 0) {
            int r2 = r | j;
            bool asc = (((lane << 3) | r) & k) == 0;
            float a = v[r], b = v[r2];
            float lo = fminf(a, b), hi = fmaxf(a, b);
            v[r]  = asc ? lo : hi;
            v[r2] = asc ? hi : lo;
          }
        }
      }
    }
  }
}

// ---------------------------------------------------------------------------
// Fused: per-(b,d) order stats + affine map + attention + err(bf16) + ymean
// + bn partial sums (atomicAdd).
// ---------------------------------------------------------------------------
__global__ __launch_bounds__(256) void fused_kernel(
    const float* __restrict__ x, const float* __restrict__ xt,
    const float* __restrict__ y_date,
    float* __restrict__ V, float* __restrict__ ymean,
    unsigned short* __restrict__ errb, float* __restrict__ accum) {
  __shared__ float lds[LDSF];
  int bid = blockIdx.x, b = bid >> 5, d = bid & 31;
  int tid = threadIdx.x, lane = tid & 63, wv = tid >> 6;

  // ---- stage 6 contiguous xt rows into LDS cols; x strided into col 6 ----
  const float* xtb = xt + (size_t)(b * 192 + d * 6) * LL;
  #pragma unroll
  for (int it = 0; it < 3; ++it) {
    int f = tid + it * 256;                    // 0..767 = 6 cols x 128 float4
    int c = f >> 7, c4 = f & 127;
    float4 v = ((const float4*)(xtb + (size_t)c * LL))[c4];
    *(float4*)&lds[XCOL + c * CSTR + c4 * 4] = v;
  }
  const float* xp = x + (size_t)b * LL * DD + d;
  lds[XV + tid]       = xp[(size_t)tid * DD];
  lds[XV + tid + 256] = xp[(size_t)(tid + 256) * DD];
  __syncthreads();

  // ---- sort 7 sequences (2 passes of 4 waves) ----
  #pragma unroll
  for (int pass = 0; pass < 2; ++pass) {
    int s = pass * 4 + wv;
    if (s < 7) {
      float v[8];
      const float4* colp = (const float4*)&lds[XCOL + s * CSTR + lane * 8];
      float4 c0 = colp[0], c1 = colp[1];
      v[0]=c0.x; v[1]=c0.y; v[2]=c0.z; v[3]=c0.w;
      v[4]=c1.x; v[5]=c1.y; v[6]=c1.z; v[7]=c1.w;
      sort512(v, lane);
      float e127 = __shfl(v[7], 15);
      float e128 = __shfl(v[0], 16);
      float e255 = __shfl(v[7], 31);
      float e383 = __shfl(v[7], 47);
      float e384 = __shfl(v[0], 48);
      if (lane == 0) {
        float q25 = e127 + 0.75f * (e128 - e127);   // 0.25*(n-1)=127.75
        float q75 = e383 + 0.25f * (e384 - e383);   // 0.75*(n-1)=383.25
        lds[MEDO + s] = e255;                       // torch lower-median
        lds[STDO + s] = q75 - q25 + 1e-6f;
      }
    }
  }
  __syncthreads();

  if (tid < 6) {
    float a = lds[STDO + 6] / lds[STDO + tid];
    lds[SAO + tid] = a;
    lds[SCO + tid] = lds[MEDO + 6] - lds[MEDO + tid] * a;
  }
  __syncthreads();

  float ask[6], csk[6];
  #pragma unroll
  for (int k = 0; k < 6; ++k) { ask[k] = lds[SAO + k]; csk[k] = lds[SCO + k]; }

  const float PSC = 0.58912435f;   // (1/sqrt(6)) * log2(e)

  // ---- transform rows tid, tid+256 into regs (f16-packed, x-side prescaled) ----
  float4 packed[2];
  #pragma unroll
  for (int it = 0; it < 2; ++it) {
    int l = tid + it * 256;
    float m0 = ask[0]*lds[XCOL+0*CSTR+l] + csk[0];
    float m1 = ask[1]*lds[XCOL+1*CSTR+l] + csk[1];
    float m2 = ask[2]*lds[XCOL+2*CSTR+l] + csk[2];
    float m3 = ask[3]*lds[XCOL+3*CSTR+l] + csk[3];
    float m4 = ask[4]*lds[XCOL+4*CSTR+l] + csk[4];
    float m5 = ask[5]*lds[XCOL+5*CSTR+l] + csk[5];
    float xvv = lds[XV + l];
    errb[(size_t)bid * LL + l] = f2bf(xvv - (m0+m1+m2+m3+m4+m5) * (1.0f/6.0f));
    packed[it].x = asF(__builtin_amdgcn_cvt_pkrtz(m0*PSC, m1*PSC));
    packed[it].y = asF(__builtin_amdgcn_cvt_pkrtz(m2*PSC, m3*PSC));
    packed[it].z = asF(__builtin_amdgcn_cvt_pkrtz(m4*PSC, m5*PSC));
    packed[it].w = asF(__builtin_amdgcn_cvt_pkrtz(xvv, 0.0f));
  }

  // ---- y staging (threads 0..191): direct strided reads (L2-absorbed) ----
  float4 ypk; float ymv; bool doY = (tid < OO);
  if (doY) {
    const float2* yp = (const float2*)(y_date + (((size_t)b * OO + tid) * DD + d) * KK);
    float2 y0 = yp[0], y1 = yp[1], y2 = yp[2];
    float q0 = ask[0]*y0.x + csk[0];
    float q1 = ask[1]*y0.y + csk[1];
    float q2 = ask[2]*y1.x + csk[2];
    float q3 = ask[3]*y1.y + csk[3];
    float q4 = ask[4]*y2.x + csk[4];
    float q5 = ask[5]*y2.y + csk[5];
    ymv = (q0+q1+q2+q3+q4+q5) * (1.0f/6.0f);
    ypk.x = asF(__builtin_amdgcn_cvt_pkrtz(q0, q1));
    ypk.y = asF(__builtin_amdgcn_cvt_pkrtz(q2, q3));
    ypk.z = asF(__builtin_amdgcn_cvt_pkrtz(q4, q5));
  }
  __syncthreads();   // all XCOL col0-5 reads done; safe to overlay

  // ---- write f16 rows (overlay XCOL cols 0-5) + YDM; load yk frags ----
  *(float4*)&lds[tid * 4]         = packed[0];
  *(float4*)&lds[(tid + 256) * 4] = packed[1];
  if (doY) {
    ymean[(size_t)bid * OO + tid] = ymv;
    lds[YDMB + tid*4 + 0] = ypk.x;
    lds[YDMB + tid*4 + 1] = ypk.y;
    lds[YDMB + tid*4 + 2] = ypk.z;
  }
  __syncthreads();

  h2 yk[3][3];
  #pragma unroll
  for (int j = 0; j < 3; ++j) {
    int o = lane + 64 * j;
    yk[j][0] = asH(lds[YDMB + o*4 + 0]);
    yk[j][1] = asH(lds[YDMB + o*4 + 1]);
    yk[j][2] = asH(lds[YDMB + o*4 + 2]);
  }
  __syncthreads();   // yk loaded; DEN/NUM may overlay YDM after this

  // ---- attention: wave wv handles l in [wv*128, +128), 3 o's/lane ----
  float den[3] = {0.f,0.f,0.f}, num[3] = {0.f,0.f,0.f};
  int l0 = wv * 128;
  #pragma unroll 2
  for (int l = l0; l < l0 + 128; ++l) {
    float4 rw = *(const float4*)&lds[l * 4];
    h2 x01 = asH(rw.x), x23 = asH(rw.y), x45 = asH(rw.z);
    float xf = (float)(asH(rw.w).x);
    #pragma unroll
    for (int j = 0; j < 3; ++j) {
      float sc = __builtin_amdgcn_fdot2(x01, yk[j][0], 0.0f, false);
      sc = __builtin_amdgcn_fdot2(x23, yk[j][1], sc, false);
      sc = __builtin_amdgcn_fdot2(x45, yk[j][2], sc, false);
      float e = exp2f(sc);     // scale folded into x-side pack
      den[j] += e;
      num[j] += e * xf;
    }
  }
  #pragma unroll
  for (int j = 0; j < 3; ++j) {
    lds[YDMB + wv*192 + lane + 64*j]       = den[j];
    lds[YDMB + 768 + wv*192 + lane + 64*j] = num[j];
  }
  __syncthreads();

  float v = 0.0f;
  if (tid < OO) {
    float dsum = lds[YDMB + tid] + lds[YDMB + 192 + tid]
               + lds[YDMB + 384 + tid] + lds[YDMB + 576 + tid];
    float nsum = lds[YDMB + 768 + tid] + lds[YDMB + 960 + tid]
               + lds[YDMB + 1152 + tid] + lds[YDMB + 1344 + tid];
    v = nsum / dsum;
    V[(size_t)bid * OO + tid] = v;
  }

  // ---- bn partial sums over this block's 192 V values -> atomicAdd per d ----
  __syncthreads();                 // YDMB reads done; BNP overlays safe
  float s1 = v, s2 = v * v;
  #pragma unroll
  for (int off = 32; off > 0; off >>= 1) {
    s1 += __shfl_down(s1, off);
    s2 += __shfl_down(s2, off);
  }
  if (lane == 0) { lds[BNP + wv] = s1; lds[BNP + 4 + wv] = s2; }
  __syncthreads();
  if (tid == 0) {
    float S  = lds[BNP+0] + lds[BNP+1] + lds[BNP+2] + lds[BNP+3];
    float S2 = lds[BNP+4] + lds[BNP+5] + lds[BNP+6] + lds[BNP+7];
    atomicAdd(&accum[d], S);
    atomicAdd(&accum[DD + d], S2);
  }
}

// ---------------------------------------------------------------------------
// Gating MLP via MFMA GEMM: H = errb(1024x512,bf16) @ w1t^T(512x512,bf16).
// 32 blocks x 4 waves; block = 32 rows x 512 m; wave = 32 rows x 128 m.
// A frag: lane holds errb[r0 + rt*16 + (lane&15)][ks + quad*8 + j].
// B frag: lane holds w1t[mw + ct*16 + (lane&15)][ks + quad*8 + j].
// C frag: row = quad*4 + reg, col = lane&15  (layout verified in R7).
// ---------------------------------------------------------------------------
__global__ __launch_bounds__(256) void mlp_kernel(
    const unsigned short* __restrict__ errb, const unsigned short* __restrict__ w1t,
    const float* __restrict__ b1, const float* __restrict__ w2,
    const float* __restrict__ b2, float* __restrict__ w0out) {
  int r0 = blockIdx.x * 32;
  int tid = threadIdx.x, lane = tid & 63, wv = tid >> 6;
  int m16 = lane & 15, quad = lane >> 4;
  int mw = wv * 128;

  float b1v[8], w2d[8];
  #pragma unroll
  for (int ct = 0; ct < 8; ++ct) {
    int m = mw + ct * 16 + m16;
    b1v[ct] = b1[m];
    float2 w2p = ((const float2*)w2)[m];
    w2d[ct] = w2p.x - w2p.y;
  }

  f4 acc[2][8];
  #pragma unroll
  for (int rt = 0; rt < 2; ++rt)
    #pragma unroll
    for (int ct = 0; ct < 8; ++ct)
      acc[rt][ct] = (f4){0.f, 0.f, 0.f, 0.f};

  const unsigned short* ea = errb + (size_t)(r0 + m16) * DM + quad * 8;
  const unsigned short* eb = ea + 16 * DM;
  const unsigned short* wb = w1t + (size_t)(mw + m16) * DM + quad * 8;

  for (int ks = 0; ks < DM; ks += 32) {
    U16x8 ua0, ua1;
    ua0.u = *(const uint4*)(ea + ks);
    ua1.u = *(const uint4*)(eb + ks);
    #pragma unroll
    for (int ct = 0; ct < 8; ++ct) {
      U16x8 ub;
      ub.u = *(const uint4*)(wb + (size_t)ct * 16 * DM + ks);
      acc[0][ct] = __builtin_amdgcn_mfma_f32_16x16x32_bf16(ua0.h, ub.h, acc[0][ct], 0, 0, 0);
      acc[1][ct] = __builtin_amdgcn_mfma_f32_16x16x32_bf16(ua1.h, ub.h, acc[1][ct], 0, 0, 0);
    }
  }

  __shared__ float part[4][32];
  #pragma unroll
  for (int rt = 0; rt < 2; ++rt) {
    float rsum[4] = {0.f, 0.f, 0.f, 0.f};
    #pragma unroll
    for (int ct = 0; ct < 8; ++ct) {
      #pragma unroll
      for (int r = 0; r < 4; ++r) {
        float h = acc[rt][ct][r] + b1v[ct];
        float g = 0.5f * h * (1.0f + erff(h * 0.70710678f));
        rsum[r] += g * w2d[ct];
      }
    }
    #pragma unroll
    for (int r = 0; r < 4; ++r) {
      rsum[r] += __shfl_xor(rsum[r], 1);
      rsum[r] += __shfl_xor(rsum[r], 2);
      rsum[r] += __shfl_xor(rsum[r], 4);
      rsum[r] += __shfl_xor(rsum[r], 8);
    }
    if (m16 == 0) {
      #pragma unroll
      for (int r = 0; r < 4; ++r)
        part[wv][rt * 16 + quad * 4 + r] = rsum[r];
    }
  }
  __syncthreads();
  if (tid < 32) {
    float ld = b2[0] - b2[1]
             + part[0][tid] + part[1][tid] + part[2][tid] + part[3][tid];
    w0out[r0 + tid] = 1.0f / (1.0f + expf(-ld));
  }
}

// ---------------------------------------------------------------------------
// Final fusion via LDS transpose; computes mu/rstd from global accumulators.
// ---------------------------------------------------------------------------
__global__ __launch_bounds__(256) void final_kernel(
    const float* __restrict__ V, const float* __restrict__ ymean,
    const float* __restrict__ w0, const float* __restrict__ accum,
    const float* __restrict__ gamma, const float* __restrict__ beta,
    float* __restrict__ out) {
  __shared__ float vsh[32 * 100], ysh[32 * 100];
  __shared__ float gate[32], scal[32], offs[32];
  int bid = blockIdx.x, b = bid >> 1, o0 = (bid & 1) * 96;
  int tid = threadIdx.x;

  #pragma unroll
  for (int it = 0; it < 3; ++it) {
    int f = tid + it * 256;
    int d = f / 24, c4 = f % 24;
    size_t goff = (size_t)(b * DD + d) * OO + o0;
    float4 v = ((const float4*)(V + goff))[c4];
    float4 y = ((const float4*)(ymean + goff))[c4];
    float* pv = &vsh[d * 100 + c4 * 4];
    float* py = &ysh[d * 100 + c4 * 4];
    pv[0]=v.x; pv[1]=v.y; pv[2]=v.z; pv[3]=v.w;
    py[0]=y.x; py[1]=y.y; py[2]=y.z; py[3]=y.w;
  }
  if (tid < 32) {
    const float inv = 1.0f / (BB * OO);
    float mu = accum[tid] * inv;
    float var = accum[DD + tid] * inv - mu * mu;
    float g = gamma[tid] * rsqrtf(var + 1e-5f);
    gate[tid] = w0[b * DD + tid];
    scal[tid] = g;
    offs[tid] = beta[tid] - mu * g;
  }
  __syncthreads();

  #pragma unroll
  for (int it = 0; it < 3; ++it) {
    int f = tid + it * 256;
    int op = f / 8, c4 = f % 8;
    float4 r;
    #pragma unroll
    for (int j = 0; j < 4; ++j) {
      int d = c4 * 4 + j;
      float v  = vsh[d * 100 + op];
      float ym = ysh[d * 100 + op];
      float g  = gate[d];
      float y  = v * scal[d] + offs[d];
      ((float*)&r)[j] = ym * g + y * (1.0f - g);
    }
    ((float4*)(out + (size_t)(b * OO + o0 + op) * DD))[c4] = r;
  }
}

// ---------------------------------------------------------------------------
extern "C" void kernel_launch(void* const* d_in, const int* in_sizes, int n_in,
                              void* d_out, int out_size, void* d_ws, size_t ws_size,
                              hipStream_t stream) {
  const float* x      = (const float*)d_in[0];
  const float* x_date = (const float*)d_in[1];
  const float* y_date = (const float*)d_in[2];
  const float* w1     = (const float*)d_in[3];
  const float* b1     = (const float*)d_in[4];
  const float* w2     = (const float*)d_in[5];
  const float* b2     = (const float*)d_in[6];
  const float* gamma  = (const float*)d_in[7];
  const float* beta   = (const float*)d_in[8];
  float* out = (float*)d_out;

  float* ws    = (float*)d_ws;
  float* V     = ws;                             // 196608  (B,D,O)
  float* ymean = ws + 196608;                    // 196608  (B,D,O)
  unsigned short* errb = (unsigned short*)(ws + 393216);   // 1024x512 bf16
  float* w0    = ws + 655360;                    // 1024    (B,D)
  float* accum = ws + 656384;                    // 64      (sum, sumsq per d)
  float* xt    = ws + 656448;                    // 3145728 (B,192,L)
  unsigned short* w1t = (unsigned short*)(ws + 3802176);   // 512x512 bf16 (m,l)

  hipMemsetAsync(accum, 0, 64 * sizeof(float), stream);
  prep_kernel<<<576, 256, 0, stream>>>(x_date, xt, w1, w1t);
  fused_kernel<<<BB * DD, 256, 0, stream>>>(x, xt, y_date, V, ymean, errb, accum);
  mlp_kernel<<<BB * DD / 32, 256, 0, stream>>>(errb, w1t, b1, w2, b2, w0);
  final_kernel<<<2 * BB, 256, 0, stream>>>(V, ymean, w0, accum, gamma, beta, out);
}

// Round 10
// 164.129 us; speedup vs baseline: 1.2097x; 1.0197x over previous
//
#include <hip/hip_runtime.h>
#include <math.h>

#define BB 32
#define LL 512
#define DD 32
#define KK 6
#define OO 192
#define DM 512

typedef __fp16 h2 __attribute__((ext_vector_type(2)));
union F2H { float f; h2 h; };
__device__ __forceinline__ float asF(h2 h) { F2H u; u.h = h; return u.f; }
__device__ __forceinline__ h2 asH(float f) { F2H u; u.f = f; return u.h; }

typedef short bf16x8 __attribute__((ext_vector_type(8)));
typedef float f4 __attribute__((ext_vector_type(4)));
union U16x8 { uint4 u; bf16x8 h; };

__device__ __forceinline__ unsigned short f2bf(float x) {   // RNE f32->bf16
  unsigned int u = __float_as_uint(x);
  u = (u + 0x7FFF + ((u >> 16) & 1)) >> 16;
  return (unsigned short)u;
}

#define MOVDPP(x, ctrl) \
  __int_as_float(__builtin_amdgcn_mov_dpp(__float_as_int(x), ctrl, 0xf, 0xf, true))

// LDS layout (float slots) for fused kernel
#define CSTR  520
#define XCOL  0                 // 7 cols x 520 f32; cols 0-5 overlaid by f16 rows later
#define XV    3120              // = XCOL + 6*CSTR : x column stays f32
#define YDMB  3648              // 192 x 4 (packed y f16); overlaid by DEN/NUM 2x768
#define BNP   5184              // 8 floats bn partials (overlays dead MEDO/STDO)
#define MEDO  5184
#define STDO  5191
#define SAO   5198
#define SCO   5204
#define LDSF  5216              // 20.9 KB

// ---------------------------------------------------------------------------
// Prep v2:
//  bids 0..255  : (b, l-chunk of 64): x_date -> xt (b,dk,l) AND x -> xt2 (b,d,l)
//                 64-row tiles: xt writes are 256B-contiguous per dk row.
//  bids 256..319: w1 (l,m) f32 -> w1t (m,l) bf16 (64x64 tiles)
// ---------------------------------------------------------------------------
__global__ __launch_bounds__(256) void prep_kernel(
    const float* __restrict__ x, const float* __restrict__ x_date,
    float* __restrict__ xt, float* __restrict__ xt2,
    const float* __restrict__ w1, unsigned short* __restrict__ w1t) {
  int bid = blockIdx.x, tid = threadIdx.x;

  if (bid < 256) {
    __shared__ float tl[64 * 197];   // 50.4 KB, stride 197 kills transpose conflicts
    __shared__ float tx[64 * 37];    // 9.5 KB
    int b = bid >> 3, l0 = (bid & 7) * 64;

    const float* src = x_date + (size_t)(b * LL + l0) * 192;
    #pragma unroll
    for (int it = 0; it < 12; ++it) {           // 64 rows x 48 float4 reads
      int f = tid + it * 256;
      int row = f / 48, c4 = f % 48;
      float4 v = ((const float4*)(src + (size_t)row * 192))[c4];
      float* p = &tl[row * 197 + c4 * 4];
      p[0] = v.x; p[1] = v.y; p[2] = v.z; p[3] = v.w;
    }
    const float* srcx = x + (size_t)(b * LL + l0) * DD;
    #pragma unroll
    for (int it = 0; it < 2; ++it) {            // 64 rows x 8 float4
      int f = tid + it * 256;
      int row = f >> 3, c4 = f & 7;
      float4 v = ((const float4*)srcx)[f];
      float* p = &tx[row * 37 + c4 * 4];
      p[0] = v.x; p[1] = v.y; p[2] = v.z; p[3] = v.w;
    }
    __syncthreads();

    #pragma unroll
    for (int it = 0; it < 12; ++it) {           // 192 dk-rows x 16 float4 (256B runs)
      int f = tid + it * 256;
      int dk = f >> 4, c4 = f & 15;
      float4 v;
      v.x = tl[(c4 * 4 + 0) * 197 + dk];
      v.y = tl[(c4 * 4 + 1) * 197 + dk];
      v.z = tl[(c4 * 4 + 2) * 197 + dk];
      v.w = tl[(c4 * 4 + 3) * 197 + dk];
      ((float4*)(xt + (size_t)(b * 192 + dk) * LL + l0))[c4] = v;
    }
    #pragma unroll
    for (int it = 0; it < 2; ++it) {            // 32 d-rows x 16 float4
      int f = tid + it * 256;
      int d = f >> 4, c4 = f & 15;
      float4 v;
      v.x = tx[(c4 * 4 + 0) * 37 + d];
      v.y = tx[(c4 * 4 + 1) * 37 + d];
      v.z = tx[(c4 * 4 + 2) * 37 + d];
      v.w = tx[(c4 * 4 + 3) * 37 + d];
      ((float4*)(xt2 + (size_t)(b * DD + d) * LL + l0))[c4] = v;
    }
  } else {
    // ---- w1 -> w1t bf16, 64x64 tile ----
    __shared__ float tw[64 * 68];
    int id = bid - 256;                         // 0..63
    int l0 = (id & 7) * 64, m0 = (id >> 3) * 64;
    #pragma unroll
    for (int it = 0; it < 4; ++it) {            // 64 l-rows x 16 float4
      int f = tid + it * 256;
      int row = f >> 4, c4 = f & 15;
      float4 v = ((const float4*)(w1 + (size_t)(l0 + row) * DM + m0))[c4];
      float* p = &tw[row * 68 + c4 * 4];
      p[0] = v.x; p[1] = v.y; p[2] = v.z; p[3] = v.w;
    }
    __syncthreads();
    unsigned int* w1t32 = (unsigned int*)w1t;
    #pragma unroll
    for (int it = 0; it < 8; ++it) {            // 64 m-rows x 32 uints
      int f = tid + it * 256;
      int mr = f >> 5, c = f & 31;
      float a = tw[(c * 2 + 0) * 68 + mr];
      float b = tw[(c * 2 + 1) * 68 + mr];
      unsigned int u = (unsigned int)f2bf(a) | ((unsigned int)f2bf(b) << 16);
      w1t32[(size_t)(m0 + mr) * (DM / 2) + (l0 >> 1) + c] = u;
    }
  }
}

// ---------------------------------------------------------------------------
// In-register bitonic sort of 512 floats across one wave (8 elems/lane).
// Lane-xor 1/2/8 via DPP (VALU pipe); 4/16/32 via shfl (LDS pipe).
// ---------------------------------------------------------------------------
__device__ __forceinline__ void sort512(float v[8], int lane) {
  #pragma unroll
  for (int k = 2; k <= 512; k <<= 1) {
    #pragma unroll
    for (int j = k >> 1; j > 0; j >>= 1) {
      if (j >= 8) {
        int jj = j >> 3;
        bool lower = (lane & jj) == 0;
        bool asc = ((lane << 3) & k) == 0;
        bool keepmin = (asc == lower);
        #pragma unroll
        for (int r = 0; r < 8; ++r) {
          float o;
          if (jj == 1)      o = MOVDPP(v[r], 0xB1);   // quad_perm [1,0,3,2]
          else if (jj == 2) o = MOVDPP(v[r], 0x4E);   // quad_perm [2,3,0,1]
          else if (jj == 8) o = MOVDPP(v[r], 0x128);  // row_ror:8 == xor8
          else              o = __shfl_xor(v[r], jj);
          v[r] = keepmin ? fminf(v[r], o) : fmaxf(v[r], o);
        }
      } else {
        #pragma unroll
        for (int r = 0; r < 8; ++r) {
          if ((r & j) == 0) {
            int r2 = r | j;
            bool asc = (((lane << 3) | r) & k) == 0;
            float a = v[r], b = v[r2];
            float lo = fminf(a, b), hi = fmaxf(a, b);
            v[r]  = asc ? lo : hi;
            v[r2] = asc ? hi : lo;
          }
        }
      }
    }
  }
}

// ---------------------------------------------------------------------------
// Fused: per-(b,d) order stats + affine map + attention + err(bf16) + ymean
// + bn partial sums (atomicAdd). All staging reads coalesced (xt, xt2).
// ---------------------------------------------------------------------------
__global__ __launch_bounds__(256) void fused_kernel(
    const float* __restrict__ xt, const float* __restrict__ xt2,
    const float* __restrict__ y_date,
    float* __restrict__ V, float* __restrict__ ymean,
    unsigned short* __restrict__ errb, float* __restrict__ accum) {
  __shared__ float lds[LDSF];
  int bid = blockIdx.x, b = bid >> 5, d = bid & 31;
  int tid = threadIdx.x, lane = tid & 63, wv = tid >> 6;

  // ---- stage 6 xt rows + 1 xt2 row, all coalesced b128 ----
  const float* xtb = xt + (size_t)(b * 192 + d * 6) * LL;
  #pragma unroll
  for (int it = 0; it < 3; ++it) {
    int f = tid + it * 256;                    // 0..767 = 6 cols x 128 float4
    int c = f >> 7, c4 = f & 127;
    float4 v = ((const float4*)(xtb + (size_t)c * LL))[c4];
    *(float4*)&lds[XCOL + c * CSTR + c4 * 4] = v;
  }
  if (tid < 128) {
    float4 v = ((const float4*)(xt2 + (size_t)(b * DD + d) * LL))[tid];
    *(float4*)&lds[XV + tid * 4] = v;
  }
  __syncthreads();

  // ---- sort 7 sequences (2 passes of 4 waves) ----
  #pragma unroll
  for (int pass = 0; pass < 2; ++pass) {
    int s = pass * 4 + wv;
    if (s < 7) {
      float v[8];
      const float4* colp = (s < 6) ? (const float4*)&lds[XCOL + s * CSTR + lane * 8]
                                   : (const float4*)&lds[XV + lane * 8];
      float4 c0 = colp[0], c1 = colp[1];
      v[0]=c0.x; v[1]=c0.y; v[2]=c0.z; v[3]=c0.w;
      v[4]=c1.x; v[5]=c1.y; v[6]=c1.z; v[7]=c1.w;
      sort512(v, lane);
      float e127 = __shfl(v[7], 15);
      float e128 = __shfl(v[0], 16);
      float e255 = __shfl(v[7], 31);
      float e383 = __shfl(v[7], 47);
      float e384 = __shfl(v[0], 48);
      if (lane == 0) {
        float q25 = e127 + 0.75f * (e128 - e127);   // 0.25*(n-1)=127.75
        float q75 = e383 + 0.25f * (e384 - e383);   // 0.75*(n-1)=383.25
        lds[MEDO + s] = e255;                       // torch lower-median
        lds[STDO + s] = q75 - q25 + 1e-6f;
      }
    }
  }
  __syncthreads();

  if (tid < 6) {
    float a = lds[STDO + 6] / lds[STDO + tid];
    lds[SAO + tid] = a;
    lds[SCO + tid] = lds[MEDO + 6] - lds[MEDO + tid] * a;
  }
  __syncthreads();

  float ask[6], csk[6];
  #pragma unroll
  for (int k = 0; k < 6; ++k) { ask[k] = lds[SAO + k]; csk[k] = lds[SCO + k]; }

  const float PSC = 0.58912435f;   // (1/sqrt(6)) * log2(e)

  // ---- transform rows tid, tid+256 into regs (f16-packed, x-side prescaled) ----
  float4 packed[2];
  #pragma unroll
  for (int it = 0; it < 2; ++it) {
    int l = tid + it * 256;
    float m0 = ask[0]*lds[XCOL+0*CSTR+l] + csk[0];
    float m1 = ask[1]*lds[XCOL+1*CSTR+l] + csk[1];
    float m2 = ask[2]*lds[XCOL+2*CSTR+l] + csk[2];
    float m3 = ask[3]*lds[XCOL+3*CSTR+l] + csk[3];
    float m4 = ask[4]*lds[XCOL+4*CSTR+l] + csk[4];
    float m5 = ask[5]*lds[XCOL+5*CSTR+l] + csk[5];
    float xvv = lds[XV + l];
    errb[(size_t)bid * LL + l] = f2bf(xvv - (m0+m1+m2+m3+m4+m5) * (1.0f/6.0f));
    packed[it].x = asF(__builtin_amdgcn_cvt_pkrtz(m0*PSC, m1*PSC));
    packed[it].y = asF(__builtin_amdgcn_cvt_pkrtz(m2*PSC, m3*PSC));
    packed[it].z = asF(__builtin_amdgcn_cvt_pkrtz(m4*PSC, m5*PSC));
    packed[it].w = asF(__builtin_amdgcn_cvt_pkrtz(xvv, 0.0f));
  }

  // ---- y staging (threads 0..191): direct strided reads (L2-absorbed) ----
  float4 ypk; float ymv; bool doY = (tid < OO);
  if (doY) {
    const float2* yp = (const float2*)(y_date + (((size_t)b * OO + tid) * DD + d) * KK);
    float2 y0 = yp[0], y1 = yp[1], y2 = yp[2];
    float q0 = ask[0]*y0.x + csk[0];
    float q1 = ask[1]*y0.y + csk[1];
    float q2 = ask[2]*y1.x + csk[2];
    float q3 = ask[3]*y1.y + csk[3];
    float q4 = ask[4]*y2.x + csk[4];
    float q5 = ask[5]*y2.y + csk[5];
    ymv = (q0+q1+q2+q3+q4+q5) * (1.0f/6.0f);
    ypk.x = asF(__builtin_amdgcn_cvt_pkrtz(q0, q1));
    ypk.y = asF(__builtin_amdgcn_cvt_pkrtz(q2, q3));
    ypk.z = asF(__builtin_amdgcn_cvt_pkrtz(q4, q5));
  }
  __syncthreads();   // all XCOL col0-5 reads done; safe to overlay

  // ---- write f16 rows (overlay XCOL cols 0-5) + YDM; load yk frags ----
  *(float4*)&lds[tid * 4]         = packed[0];
  *(float4*)&lds[(tid + 256) * 4] = packed[1];
  if (doY) {
    ymean[(size_t)bid * OO + tid] = ymv;
    lds[YDMB + tid*4 + 0] = ypk.x;
    lds[YDMB + tid*4 + 1] = ypk.y;
    lds[YDMB + tid*4 + 2] = ypk.z;
  }
  __syncthreads();

  h2 yk[3][3];
  #pragma unroll
  for (int j = 0; j < 3; ++j) {
    int o = lane + 64 * j;
    yk[j][0] = asH(lds[YDMB + o*4 + 0]);
    yk[j][1] = asH(lds[YDMB + o*4 + 1]);
    yk[j][2] = asH(lds[YDMB + o*4 + 2]);
  }
  __syncthreads();   // yk loaded; DEN/NUM may overlay YDM after this

  // ---- attention: wave wv handles l in [wv*128, +128), 3 o's/lane ----
  float den[3] = {0.f,0.f,0.f}, num[3] = {0.f,0.f,0.f};
  int l0 = wv * 128;
  #pragma unroll 2
  for (int l = l0; l < l0 + 128; ++l) {
    float4 rw = *(const float4*)&lds[l * 4];
    h2 x01 = asH(rw.x), x23 = asH(rw.y), x45 = asH(rw.z);
    float xf = (float)(asH(rw.w).x);
    #pragma unroll
    for (int j = 0; j < 3; ++j) {
      float sc = __builtin_amdgcn_fdot2(x01, yk[j][0], 0.0f, false);
      sc = __builtin_amdgcn_fdot2(x23, yk[j][1], sc, false);
      sc = __builtin_amdgcn_fdot2(x45, yk[j][2], sc, false);
      float e = exp2f(sc);     // scale folded into x-side pack
      den[j] += e;
      num[j] += e * xf;
    }
  }
  #pragma unroll
  for (int j = 0; j < 3; ++j) {
    lds[YDMB + wv*192 + lane + 64*j]       = den[j];
    lds[YDMB + 768 + wv*192 + lane + 64*j] = num[j];
  }
  __syncthreads();

  float v = 0.0f;
  if (tid < OO) {
    float dsum = lds[YDMB + tid] + lds[YDMB + 192 + tid]
               + lds[YDMB + 384 + tid] + lds[YDMB + 576 + tid];
    float nsum = lds[YDMB + 768 + tid] + lds[YDMB + 960 + tid]
               + lds[YDMB + 1152 + tid] + lds[YDMB + 1344 + tid];
    v = nsum / dsum;
    V[(size_t)bid * OO + tid] = v;
  }

  // ---- bn partial sums over this block's 192 V values -> atomicAdd per d ----
  __syncthreads();                 // YDMB reads done; BNP overlays safe
  float s1 = v, s2 = v * v;
  #pragma unroll
  for (int off = 32; off > 0; off >>= 1) {
    s1 += __shfl_down(s1, off);
    s2 += __shfl_down(s2, off);
  }
  if (lane == 0) { lds[BNP + wv] = s1; lds[BNP + 4 + wv] = s2; }
  __syncthreads();
  if (tid == 0) {
    float S  = lds[BNP+0] + lds[BNP+1] + lds[BNP+2] + lds[BNP+3];
    float S2 = lds[BNP+4] + lds[BNP+5] + lds[BNP+6] + lds[BNP+7];
    atomicAdd(&accum[d], S);
    atomicAdd(&accum[DD + d], S2);
  }
}

// ---------------------------------------------------------------------------
// Gating MLP via MFMA GEMM, 64 blocks x 4 waves; block = 16 rows x 512 m.
// A frag: lane holds errb[r0 + (lane&15)][ks + quad*8 + j].
// B frag: lane holds w1t[mw + ct*16 + (lane&15)][ks + quad*8 + j].
// C frag: row = quad*4 + reg, col = lane&15.
// ---------------------------------------------------------------------------
__global__ __launch_bounds__(256) void mlp_kernel(
    const unsigned short* __restrict__ errb, const unsigned short* __restrict__ w1t,
    const float* __restrict__ b1, const float* __restrict__ w2,
    const float* __restrict__ b2, float* __restrict__ w0out) {
  int r0 = blockIdx.x * 16;
  int tid = threadIdx.x, lane = tid & 63, wv = tid >> 6;
  int m16 = lane & 15, quad = lane >> 4;
  int mw = wv * 128;

  float b1v[8], w2d[8];
  #pragma unroll
  for (int ct = 0; ct < 8; ++ct) {
    int m = mw + ct * 16 + m16;
    b1v[ct] = b1[m];
    float2 w2p = ((const float2*)w2)[m];
    w2d[ct] = w2p.x - w2p.y;
  }

  f4 acc[8];
  #pragma unroll
  for (int ct = 0; ct < 8; ++ct) acc[ct] = (f4){0.f, 0.f, 0.f, 0.f};

  const unsigned short* ea = errb + (size_t)(r0 + m16) * DM + quad * 8;
  const unsigned short* wb = w1t + (size_t)(mw + m16) * DM + quad * 8;

  for (int ks = 0; ks < DM; ks += 32) {
    U16x8 ua;
    ua.u = *(const uint4*)(ea + ks);
    #pragma unroll
    for (int ct = 0; ct < 8; ++ct) {
      U16x8 ub;
      ub.u = *(const uint4*)(wb + (size_t)ct * 16 * DM + ks);
      acc[ct] = __builtin_amdgcn_mfma_f32_16x16x32_bf16(ua.h, ub.h, acc[ct], 0, 0, 0);
    }
  }

  __shared__ float part[4][16];
  float rsum[4] = {0.f, 0.f, 0.f, 0.f};
  #pragma unroll
  for (int ct = 0; ct < 8; ++ct) {
    #pragma unroll
    for (int r = 0; r < 4; ++r) {
      float h = acc[ct][r] + b1v[ct];
      float g = 0.5f * h * (1.0f + erff(h * 0.70710678f));
      rsum[r] += g * w2d[ct];
    }
  }
  #pragma unroll
  for (int r = 0; r < 4; ++r) {
    rsum[r] += __shfl_xor(rsum[r], 1);
    rsum[r] += __shfl_xor(rsum[r], 2);
    rsum[r] += __shfl_xor(rsum[r], 4);
    rsum[r] += __shfl_xor(rsum[r], 8);
  }
  if (m16 == 0) {
    #pragma unroll
    for (int r = 0; r < 4; ++r)
      part[wv][quad * 4 + r] = rsum[r];
  }
  __syncthreads();
  if (tid < 16) {
    float ld = b2[0] - b2[1]
             + part[0][tid] + part[1][tid] + part[2][tid] + part[3][tid];
    w0out[r0 + tid] = 1.0f / (1.0f + expf(-ld));
  }
}

// ---------------------------------------------------------------------------
// Final fusion via LDS transpose; computes mu/rstd from global accumulators.
// ---------------------------------------------------------------------------
__global__ __launch_bounds__(256) void final_kernel(
    const float* __restrict__ V, const float* __restrict__ ymean,
    const float* __restrict__ w0, const float* __restrict__ accum,
    const float* __restrict__ gamma, const float* __restrict__ beta,
    float* __restrict__ out) {
  __shared__ float vsh[32 * 100], ysh[32 * 100];
  __shared__ float gate[32], scal[32], offs[32];
  int bid = blockIdx.x, b = bid >> 1, o0 = (bid & 1) * 96;
  int tid = threadIdx.x;

  #pragma unroll
  for (int it = 0; it < 3; ++it) {
    int f = tid + it * 256;
    int d = f / 24, c4 = f % 24;
    size_t goff = (size_t)(b * DD + d) * OO + o0;
    float4 v = ((const float4*)(V + goff))[c4];
    float4 y = ((const float4*)(ymean + goff))[c4];
    float* pv = &vsh[d * 100 + c4 * 4];
    float* py = &ysh[d * 100 + c4 * 4];
    pv[0]=v.x; pv[1]=v.y; pv[2]=v.z; pv[3]=v.w;
    py[0]=y.x; py[1]=y.y; py[2]=y.z; py[3]=y.w;
  }
  if (tid < 32) {
    const float inv = 1.0f / (BB * OO);
    float mu = accum[tid] * inv;
    float var = accum[DD + tid] * inv - mu * mu;
    float g = gamma[tid] * rsqrtf(var + 1e-5f);
    gate[tid] = w0[b * DD + tid];
    scal[tid] = g;
    offs[tid] = beta[tid] - mu * g;
  }
  __syncthreads();

  #pragma unroll
  for (int it = 0; it < 3; ++it) {
    int f = tid + it * 256;
    int op = f / 8, c4 = f % 8;
    float4 r;
    #pragma unroll
    for (int j = 0; j < 4; ++j) {
      int d = c4 * 4 + j;
      float v  = vsh[d * 100 + op];
      float ym = ysh[d * 100 + op];
      float g  = gate[d];
      float y  = v * scal[d] + offs[d];
      ((float*)&r)[j] = ym * g + y * (1.0f - g);
    }
    ((float4*)(out + (size_t)(b * OO + o0 + op) * DD))[c4] = r;
  }
}

// ---------------------------------------------------------------------------
extern "C" void kernel_launch(void* const* d_in, const int* in_sizes, int n_in,
                              void* d_out, int out_size, void* d_ws, size_t ws_size,
                              hipStream_t stream) {
  const float* x      = (const float*)d_in[0];
  const float* x_date = (const float*)d_in[1];
  const float* y_date = (const float*)d_in[2];
  const float* w1     = (const float*)d_in[3];
  const float* b1     = (const float*)d_in[4];
  const float* w2     = (const float*)d_in[5];
  const float* b2     = (const float*)d_in[6];
  const float* gamma  = (const float*)d_in[7];
  const float* beta   = (const float*)d_in[8];
  float* out = (float*)d_out;

  float* ws    = (float*)d_ws;
  float* V     = ws;                             // 196608  (B,D,O)
  float* ymean = ws + 196608;                    // 196608  (B,D,O)
  unsigned short* errb = (unsigned short*)(ws + 393216);   // 1024x512 bf16
  float* w0    = ws + 655360;                    // 1024    (B,D)
  float* accum = ws + 656384;                    // 64      (sum, sumsq per d)
  float* xt    = ws + 656448;                    // 3145728 (B,192,L)
  float* xt2   = ws + 3802176;                   // 524288  (B,D,L)
  unsigned short* w1t = (unsigned short*)(ws + 4326464);   // 512x512 bf16 (m,l)

  hipMemsetAsync(accum, 0, 64 * sizeof(float), stream);
  prep_kernel<<<320, 256, 0, stream>>>(x, x_date, xt, xt2, w1, w1t);
  fused_kernel<<<BB * DD, 256, 0, stream>>>(xt, xt2, y_date, V, ymean, errb, accum);
  mlp_kernel<<<BB * DD / 16, 256, 0, stream>>>(errb, w1t, b1, w2, b2, w0);
  final_kernel<<<2 * BB, 256, 0, stream>>>(V, ymean, w0, accum, gamma, beta, out);
}